// Round 1
// baseline (192.638 us; speedup 1.0000x reference)
//
#include <hip/hip_runtime.h>
#include <hip/hip_fp16.h>

#define S_LEN    1024
#define B_SZ     8
#define D_IN     64
#define D_OUT    96
#define NB       8
#define NE       (D_OUT * D_OUT)          // 9216
#define CHUNK    32                       // s-steps per recurrence chain (was 16)
#define NCHUNK   (S_LEN / CHUNK)          // 32
#define NT_W     256
#define NWBLK    (NCHUNK * (NE / NT_W))   // 1152 blocks
#define NT_C     512                      // 8 waves
#define HPAD     104                      // f16 row pitch (52 words: 8-row quads tile 32 banks)
#define SPAD     100                      // f32 row pitch
#define XPAD     68

__device__ __forceinline__ float cos_rev(float v) {   // cos(2*pi*v), v in revolutions
    v -= floorf(v);
    return __builtin_amdgcn_cosf(v);
}

// ---------------- w_kernel: planar W1, W2 (f16) via cosine recurrence ----------------
__global__ void __launch_bounds__(NT_W)
w_kernel(const float* __restrict__ P1, const float* __restrict__ P2,
         __half* __restrict__ W1, __half* __restrict__ W2) {
    const int c  = blockIdx.x / (NE / NT_W);
    const int eb = blockIdx.x % (NE / NT_W);
    const int e  = eb * NT_W + threadIdx.x;
    const int s0 = c * CHUNK;
    const float s0f = (float)s0;

    float p1l[NB], p2l[NB];
    *(float4*)&p1l[0] = *(const float4*)(P1 + e * NB);
    *(float4*)&p1l[4] = *(const float4*)(P1 + e * NB + 4);
    *(float4*)&p2l[0] = *(const float4*)(P2 + e * NB);
    *(float4*)&p2l[4] = *(const float4*)(P2 + e * NB + 4);

    float cc[NB], cp[NB], kk[NB];
    #pragma unroll
    for (int g = 0; g < NB; ++g) {
        const float inv = __builtin_amdgcn_rcpf((float)(e * NB + 2 + g));
        cc[g] = cos_rev(s0f * inv);
        cp[g] = cos_rev((s0f - 1.0f) * inv);
        kk[g] = 2.0f * __builtin_amdgcn_cosf(inv);   // inv <= 0.5 rev
    }

    #pragma unroll 4
    for (int s = s0; s < s0 + CHUNK; ++s) {
        float a1 = 0.0f, a2 = 0.0f;
        #pragma unroll
        for (int g = 0; g < NB; ++g) {
            a1 = fmaf(p1l[g], cc[g], a1);
            a2 = fmaf(p2l[g], cc[g], a2);
        }
        W1[s * NE + e] = __float2half(a1);   // coalesced 2B/lane
        W2[s * NE + e] = __float2half(a2);
        #pragma unroll
        for (int g = 0; g < NB; ++g) {
            float cn = fmaf(kk[g], cc[g], -cp[g]);
            cp[g] = cc[g];
            cc[g] = cn;
        }
    }
}

// Nk dot: planar f16 W row (LDS, 8 lanes share -> broadcast) x f32 x-row.
// Two 6-chunk halves bound in-flight LDS-load registers (r6-proven).
__device__ __forceinline__ float nkdot(const __half* __restrict__ wrow,
                                       const float* __restrict__ xr) {
    float acc = 0.0f;
    #pragma unroll
    for (int h = 0; h < 2; ++h) {
        #pragma unroll
        for (int j = h * 6; j < h * 6 + 6; ++j) {
            float4 raw = *(const float4*)(wrow + 8 * j);
            const __half2* hp = (const __half2*)&raw;
            float2 c0 = __half22float2(hp[0]);
            float2 c1 = __half22float2(hp[1]);
            float2 c2 = __half22float2(hp[2]);
            float2 c3 = __half22float2(hp[3]);
            float4 x0 = *(const float4*)(xr + 8 * j);
            float4 x1 = *(const float4*)(xr + 8 * j + 4);
            acc = fmaf(c0.x, x0.x, acc); acc = fmaf(c0.y, x0.y, acc);
            acc = fmaf(c1.x, x0.z, acc); acc = fmaf(c1.y, x0.w, acc);
            acc = fmaf(c2.x, x1.x, acc); acc = fmaf(c2.y, x1.y, acc);
            acc = fmaf(c3.x, x1.z, acc); acc = fmaf(c3.y, x1.w, acc);
        }
    }
    return acc;
}

__device__ __forceinline__ void stage_W(__half* __restrict__ wh,
                                        const __half* __restrict__ Wg,
                                        int tid) {
    for (int cidx = tid; cidx < NE / 8; cidx += NT_C) {   // 1152 float4 chunks
        const int i = cidx / 12;
        const int j = (cidx % 12) * 8;
        *(float4*)(wh + i * HPAD + j) = *(const float4*)(Wg + cidx * 8);
    }
}

// ---------------- Consumer: 4-barrier structure, both W stages hidden under GEMV ----
// 512 thr = 8 waves; 1024 blocks = exactly 4/CU, zero tail, 32 waves/CU.
// Wave w owns batch row b=w for GEMV+LN (fused in-register); Nk keeps the
// proven (i,b) mapping (8-lane W-row broadcast, HPAD bank-tiling).
// NO min-waves clause ((512,N) produced destructive VGPR caps in r5/r9).
__global__ void __launch_bounds__(NT_C)
consumer(const float* __restrict__ seq,
         const float* __restrict__ M1, const float* __restrict__ Wres1,
         const float* __restrict__ M2,
         const float* __restrict__ g1, const float* __restrict__ b1,
         const float* __restrict__ g2, const float* __restrict__ b2,
         const __half* __restrict__ W1g, const __half* __restrict__ W2g,
         float* __restrict__ out) {
    __shared__ __align__(16) __half wh [D_OUT * HPAD];   // 19968 B (one layer at a time)
    __shared__ __align__(16) float  xn [B_SZ * SPAD];    //  3200 B
    __shared__ __align__(16) float  x1b[B_SZ * SPAD];    //  3200 B; xin alias pre-Nk1, rs after G1
    // total 26368 B

    const int s    = blockIdx.x;
    const int tid  = threadIdx.x;
    const int wv   = tid >> 6;
    const int lane = tid & 63;

    // stage seq rows (into x1b alias space). W1 stage deliberately NOT issued
    // here: anything issued before B1 gets drained AT B1 (compiler emits
    // s_waitcnt vmcnt(0) before s_barrier), exposing the HBM latency.
    {
        x1b[wv * SPAD + lane] = seq[((size_t)wv * S_LEN + s) * D_IN + lane];
    }
    __syncthreads();   // B1 (seq staged)

    // Issue W1 stage now: its loads/ds_writes drain at B2, overlapping G1.
    stage_W(wh, W1g + (size_t)s * NE, tid);

    // ---- G1+LN1 fused: wave wv computes row b=wv of xt = seq@M1^T, rs = seq@Wres1^T,
    //      reduces mu/var in-register, writes normalized xn + rs to LDS once. ----
    {
        const int b = wv;
        const float* xr = x1b + b * SPAD;                // seq row (64 f32, LDS broadcast)
        const bool lo = (lane < 32);
        float xt0 = 0.0f, rs0 = 0.0f, xt1 = 0.0f, rs1 = 0.0f;
        {
            const float4* m0 = (const float4*)(M1 + lane * D_IN);
            const float4* r0 = (const float4*)(Wres1 + lane * D_IN);
            #pragma unroll
            for (int k = 0; k < D_IN / 4; ++k) {
                float4 mv = m0[k], rv = r0[k];
                float x0 = xr[4*k], x1 = xr[4*k+1], x2 = xr[4*k+2], x3 = xr[4*k+3];
                xt0 = fmaf(mv.x, x0, fmaf(mv.y, x1, fmaf(mv.z, x2, fmaf(mv.w, x3, xt0))));
                rs0 = fmaf(rv.x, x0, fmaf(rv.y, x1, fmaf(rv.z, x2, fmaf(rv.w, x3, rs0))));
            }
        }
        if (lo) {
            const float4* m1 = (const float4*)(M1 + (lane + 64) * D_IN);
            const float4* r1 = (const float4*)(Wres1 + (lane + 64) * D_IN);
            #pragma unroll
            for (int k = 0; k < D_IN / 4; ++k) {
                float4 mv = m1[k], rv = r1[k];
                float x0 = xr[4*k], x1 = xr[4*k+1], x2 = xr[4*k+2], x3 = xr[4*k+3];
                xt1 = fmaf(mv.x, x0, fmaf(mv.y, x1, fmaf(mv.z, x2, fmaf(mv.w, x3, xt1))));
                rs1 = fmaf(rv.x, x0, fmaf(rv.y, x1, fmaf(rv.z, x2, fmaf(rv.w, x3, rs1))));
            }
        }
        float sum = xt0 + xt1;                    // xt1==0 on hi lanes
        float sq  = fmaf(xt0, xt0, xt1 * xt1);
        #pragma unroll
        for (int off = 32; off > 0; off >>= 1) {
            sum += __shfl_down(sum, off, 64);
            sq  += __shfl_down(sq,  off, 64);
        }
        sum = __shfl(sum, 0, 64);
        sq  = __shfl(sq,  0, 64);
        const float mu  = sum * (1.0f / 96.0f);
        const float var = fmaf(sq, 1.0f / 96.0f, -(mu * mu));
        const float rsc = rsqrtf(var + 1e-5f);
        // all xr reads complete (wave-lockstep) -> safe to overwrite x1b row b
        xn [b * SPAD + lane] = fmaf((xt0 - mu) * rsc, g1[lane], b1[lane]);
        x1b[b * SPAD + lane] = rs0;
        if (lo) {
            xn [b * SPAD + 64 + lane] = fmaf((xt1 - mu) * rsc, g1[64 + lane], b1[64 + lane]);
            x1b[b * SPAD + 64 + lane] = rs1;
        }
    }
    __syncthreads();   // B2 (W1 staged + xn/rs ready)

    // ---- Nk1 + residual(LDS) -> x1b ----
    for (int pass = 0; pass < 2; ++pass) {
        int idx = tid + pass * NT_C;
        if (idx < B_SZ * D_OUT) {
            int i = idx >> 3, b = idx & 7;
            x1b[b * SPAD + i] += nkdot(wh + i * HPAD, xn + b * SPAD);
        }
    }
    __syncthreads();   // B3: W1 reads + x1b writes complete

    // restage wh <- W2[s]; G2 overlaps (doesn't touch wh), B4 covers both.
    stage_W(wh, W2g + (size_t)s * NE, tid);

    // ---- G2+LN2 fused: wave wv computes row b=wv of xt2 = x1 @ M2^T ----
    {
        const int b = wv;
        const float* xr = x1b + b * SPAD;                // x1 row (96 f32)
        const bool lo = (lane < 32);
        float xt0 = 0.0f, xt1 = 0.0f;
        {
            const float4* m0 = (const float4*)(M2 + lane * D_OUT);
            #pragma unroll
            for (int k = 0; k < D_OUT / 4; ++k) {
                float4 mv = m0[k];
                xt0 = fmaf(mv.x, xr[4*k], fmaf(mv.y, xr[4*k+1],
                      fmaf(mv.z, xr[4*k+2], fmaf(mv.w, xr[4*k+3], xt0))));
            }
        }
        if (lo) {
            const float4* m1 = (const float4*)(M2 + (lane + 64) * D_OUT);
            #pragma unroll
            for (int k = 0; k < D_OUT / 4; ++k) {
                float4 mv = m1[k];
                xt1 = fmaf(mv.x, xr[4*k], fmaf(mv.y, xr[4*k+1],
                      fmaf(mv.z, xr[4*k+2], fmaf(mv.w, xr[4*k+3], xt1))));
            }
        }
        float sum = xt0 + xt1;
        float sq  = fmaf(xt0, xt0, xt1 * xt1);
        #pragma unroll
        for (int off = 32; off > 0; off >>= 1) {
            sum += __shfl_down(sum, off, 64);
            sq  += __shfl_down(sq,  off, 64);
        }
        sum = __shfl(sum, 0, 64);
        sq  = __shfl(sq,  0, 64);
        const float mu  = sum * (1.0f / 96.0f);
        const float var = fmaf(sq, 1.0f / 96.0f, -(mu * mu));
        const float rsc = rsqrtf(var + 1e-5f);
        xn[b * SPAD + lane] = fmaf((xt0 - mu) * rsc, g2[lane], b2[lane]);
        if (lo)
            xn[b * SPAD + 64 + lane] = fmaf((xt1 - mu) * rsc, g2[64 + lane], b2[64 + lane]);
    }
    __syncthreads();   // B4 (W2 staged + xn2 ready; x1b untouched since B3)

    // ---- Nk2 + identity residual -> out ----
    for (int pass = 0; pass < 2; ++pass) {
        int idx = tid + pass * NT_C;
        if (idx < B_SZ * D_OUT) {
            int i = idx >> 3, b = idx & 7;
            float acc = nkdot(wh + i * HPAD, xn + b * SPAD);
            out[((size_t)b * S_LEN + s) * D_OUT + i] = acc + x1b[b * SPAD + i];
        }
    }
}

// ---------------- Fallback (round-1 proven kernel) if ws too small ----------------
__global__ void __launch_bounds__(NT_W)
hier_fallback(const float* __restrict__ seq,  const float* __restrict__ M1,
              const float* __restrict__ P1,   const float* __restrict__ Wres1,
              const float* __restrict__ g1,   const float* __restrict__ b1,
              const float* __restrict__ M2,   const float* __restrict__ P2,
              const float* __restrict__ g2,   const float* __restrict__ b2,
              float* __restrict__ out) {
    __shared__ __align__(16) float w[D_OUT * SPAD];
    __shared__ __align__(16) float xin[B_SZ * XPAD];
    __shared__ __align__(16) float xn [B_SZ * SPAD];
    __shared__ __align__(16) float x1b[B_SZ * SPAD];
    const int s = blockIdx.x, tid = threadIdx.x;
    const float sf = (float)s;

    for (int idx = tid; idx < B_SZ * D_IN; idx += NT_W) {
        int b = idx >> 6, k = idx & (D_IN - 1);
        xin[b * XPAD + k] = seq[(b * S_LEN + s) * D_IN + k];
    }
    for (int e = tid; e < NE; e += NT_W) {
        float pl[8];
        *(float4*)&pl[0] = *(const float4*)(P1 + e * NB);
        *(float4*)&pl[4] = *(const float4*)(P1 + e * NB + 4);
        float acc = 0.0f;
        #pragma unroll
        for (int g = 0; g < NB; ++g) {
            float v = sf * __builtin_amdgcn_rcpf((float)(e * NB + 2 + g));
            acc = fmaf(pl[g], cos_rev(v), acc);
        }
        int i = e / D_OUT;
        w[e + (SPAD - D_OUT) * i] = acc;
    }
    __syncthreads();
    for (int idx = tid; idx < B_SZ * D_OUT; idx += NT_W) {
        int i = idx >> 3, b = idx & 7;
        const float4* m  = (const float4*)(M1 + i * D_IN);
        const float4* wr = (const float4*)(Wres1 + i * D_IN);
        const float*  xr = xin + b * XPAD;
        float at = 0.0f, ar = 0.0f;
        #pragma unroll
        for (int k = 0; k < D_IN / 4; ++k) {
            float4 mv = m[k], rv = wr[k];
            float x0 = xr[4*k], x1 = xr[4*k+1], x2 = xr[4*k+2], x3 = xr[4*k+3];
            at = fmaf(mv.x, x0, fmaf(mv.y, x1, fmaf(mv.z, x2, fmaf(mv.w, x3, at))));
            ar = fmaf(rv.x, x0, fmaf(rv.y, x1, fmaf(rv.z, x2, fmaf(rv.w, x3, ar))));
        }
        xn [b * SPAD + i] = at;
        x1b[b * SPAD + i] = ar;
    }
    __syncthreads();
    {
        const int b = tid >> 5, rr = tid & 31;
        float* row = xn + b * SPAD;
        float v0 = row[rr], v1 = row[rr + 32], v2 = row[rr + 64];
        float sum = v0 + v1 + v2, sq = fmaf(v0, v0, fmaf(v1, v1, v2 * v2));
        #pragma unroll
        for (int off = 16; off > 0; off >>= 1) {
            sum += __shfl_down(sum, off, 32);
            sq  += __shfl_down(sq,  off, 32);
        }
        sum = __shfl(sum, 0, 32); sq = __shfl(sq, 0, 32);
        float mu = sum * (1.0f/96.0f), var = fmaf(sq, 1.0f/96.0f, -(mu*mu));
        float rs = rsqrtf(var + 1e-5f);
        row[rr]      = fmaf((v0 - mu) * rs, g1[rr],      b1[rr]);
        row[rr + 32] = fmaf((v1 - mu) * rs, g1[rr + 32], b1[rr + 32]);
        row[rr + 64] = fmaf((v2 - mu) * rs, g1[rr + 64], b1[rr + 64]);
    }
    __syncthreads();
    for (int idx = tid; idx < B_SZ * D_OUT; idx += NT_W) {
        int i = idx >> 3, b = idx & 7;
        const float* wrow = w + i * SPAD;
        const float* xr   = xn + b * SPAD;
        float acc = 0.0f;
        #pragma unroll
        for (int j = 0; j < D_OUT / 4; ++j) {
            float4 wv = *(const float4*)(wrow + 4 * j);
            float4 xv = *(const float4*)(xr + 4 * j);
            acc = fmaf(wv.x, xv.x, fmaf(wv.y, xv.y, fmaf(wv.z, xv.z, fmaf(wv.w, xv.w, acc))));
        }
        x1b[b * SPAD + i] += acc;
    }
    __syncthreads();
    for (int e = tid; e < NE; e += NT_W) {
        float pl[8];
        *(float4*)&pl[0] = *(const float4*)(P2 + e * NB);
        *(float4*)&pl[4] = *(const float4*)(P2 + e * NB + 4);
        float acc = 0.0f;
        #pragma unroll
        for (int g = 0; g < NB; ++g) {
            float v = sf * __builtin_amdgcn_rcpf((float)(e * NB + 2 + g));
            acc = fmaf(pl[g], cos_rev(v), acc);
        }
        int i = e / D_OUT;
        w[e + (SPAD - D_OUT) * i] = acc;
    }
    for (int idx = tid; idx < B_SZ * D_OUT; idx += NT_W) {
        int i = idx >> 3, b = idx & 7;
        const float4* m  = (const float4*)(M2 + i * D_OUT);
        const float*  xr = x1b + b * SPAD;
        float at = 0.0f;
        #pragma unroll
        for (int k = 0; k < D_OUT / 4; ++k) {
            float4 mv = m[k];
            at = fmaf(mv.x, xr[4*k], fmaf(mv.y, xr[4*k+1],
                 fmaf(mv.z, xr[4*k+2], fmaf(mv.w, xr[4*k+3], at))));
        }
        xn[b * SPAD + i] = at;
    }
    __syncthreads();
    {
        const int b = tid >> 5, rr = tid & 31;
        float* row = xn + b * SPAD;
        float v0 = row[rr], v1 = row[rr + 32], v2 = row[rr + 64];
        float sum = v0 + v1 + v2, sq = fmaf(v0, v0, fmaf(v1, v1, v2 * v2));
        #pragma unroll
        for (int off = 16; off > 0; off >>= 1) {
            sum += __shfl_down(sum, off, 32);
            sq  += __shfl_down(sq,  off, 32);
        }
        sum = __shfl(sum, 0, 32); sq = __shfl(sq, 0, 32);
        float mu = sum * (1.0f/96.0f), var = fmaf(sq, 1.0f/96.0f, -(mu*mu));
        float rs = rsqrtf(var + 1e-5f);
        row[rr]      = fmaf((v0 - mu) * rs, g2[rr],      b2[rr]);
        row[rr + 32] = fmaf((v1 - mu) * rs, g2[rr + 32], b2[rr + 32]);
        row[rr + 64] = fmaf((v2 - mu) * rs, g2[rr + 64], b2[rr + 64]);
    }
    __syncthreads();
    for (int idx = tid; idx < B_SZ * D_OUT; idx += NT_W) {
        int i = idx >> 3, b = idx & 7;
        const float* wrow = w + i * SPAD;
        const float* xr   = xn + b * SPAD;
        float acc = 0.0f;
        #pragma unroll
        for (int j = 0; j < D_OUT / 4; ++j) {
            float4 wv = *(const float4*)(wrow + 4 * j);
            float4 xv = *(const float4*)(xr + 4 * j);
            acc = fmaf(wv.x, xv.x, fmaf(wv.y, xv.y, fmaf(wv.z, xv.z, fmaf(wv.w, xv.w, acc))));
        }
        out[(b * S_LEN + s) * D_OUT + i] = acc + x1b[b * SPAD + i];
    }
}

extern "C" void kernel_launch(void* const* d_in, const int* in_sizes, int n_in,
                              void* d_out, int out_size, void* d_ws, size_t ws_size,
                              hipStream_t stream) {
    const float* seq   = (const float*)d_in[0];
    const float* M1    = (const float*)d_in[1];
    const float* P1    = (const float*)d_in[2];
    const float* Wres1 = (const float*)d_in[3];
    const float* g1    = (const float*)d_in[4];
    const float* b1    = (const float*)d_in[5];
    const float* M2    = (const float*)d_in[6];
    const float* P2    = (const float*)d_in[7];
    const float* g2    = (const float*)d_in[8];
    const float* b2    = (const float*)d_in[9];
    float* out = (float*)d_out;

    const size_t need = (size_t)2 * S_LEN * NE * sizeof(__half);   // 37.75 MB
    if (ws_size >= need) {
        __half* W1 = (__half*)d_ws;
        __half* W2 = W1 + (size_t)S_LEN * NE;
        w_kernel<<<dim3(NWBLK), dim3(NT_W), 0, stream>>>(P1, P2, W1, W2);
        consumer<<<dim3(S_LEN), dim3(NT_C), 0, stream>>>(
            seq, M1, Wres1, M2, g1, b1, g2, b2, W1, W2, out);
    } else {
        hier_fallback<<<dim3(S_LEN), dim3(NT_W), 0, stream>>>(
            seq, M1, P1, Wres1, g1, b1, M2, P2, g2, b2, out);
    }
}

// Round 2
// 118.653 us; speedup vs baseline: 1.6235x; 1.6235x over previous
//
#include <hip/hip_runtime.h>
#include <hip/hip_fp16.h>

#define S_LEN    1024
#define B_SZ     8
#define D_IN     64
#define D_OUT    96
#define NB       8
#define NE       (D_OUT * D_OUT)          // 9216
#define CHUNK    32                       // s-steps per recurrence chain
#define NCHUNK   (S_LEN / CHUNK)          // 32
#define NT_W     256
#define NWBLK    (NCHUNK * (NE / NT_W))   // 1152 blocks
#define NT_C     512                      // 8 waves
#define HPAD     104                      // f16 row pitch (52 words: 8-row quads tile 32 banks)
#define SPAD     100                      // f32 row pitch
#define XPAD     68

__device__ __forceinline__ float cos_rev(float v) {   // cos(2*pi*v), v in revolutions
    v -= floorf(v);
    return __builtin_amdgcn_cosf(v);
}

// ---------------- w_kernel: planar W1, W2 (f16) via cosine recurrence ----------------
__global__ void __launch_bounds__(NT_W)
w_kernel(const float* __restrict__ P1, const float* __restrict__ P2,
         __half* __restrict__ W1, __half* __restrict__ W2) {
    const int c  = blockIdx.x / (NE / NT_W);
    const int eb = blockIdx.x % (NE / NT_W);
    const int e  = eb * NT_W + threadIdx.x;
    const int s0 = c * CHUNK;
    const float s0f = (float)s0;

    float p1l[NB], p2l[NB];
    *(float4*)&p1l[0] = *(const float4*)(P1 + e * NB);
    *(float4*)&p1l[4] = *(const float4*)(P1 + e * NB + 4);
    *(float4*)&p2l[0] = *(const float4*)(P2 + e * NB);
    *(float4*)&p2l[4] = *(const float4*)(P2 + e * NB + 4);

    float cc[NB], cp[NB], kk[NB];
    #pragma unroll
    for (int g = 0; g < NB; ++g) {
        const float inv = __builtin_amdgcn_rcpf((float)(e * NB + 2 + g));
        cc[g] = cos_rev(s0f * inv);
        cp[g] = cos_rev((s0f - 1.0f) * inv);
        kk[g] = 2.0f * __builtin_amdgcn_cosf(inv);   // inv <= 0.5 rev
    }

    #pragma unroll 4
    for (int s = s0; s < s0 + CHUNK; ++s) {
        float a1 = 0.0f, a2 = 0.0f;
        #pragma unroll
        for (int g = 0; g < NB; ++g) {
            a1 = fmaf(p1l[g], cc[g], a1);
            a2 = fmaf(p2l[g], cc[g], a2);
        }
        W1[s * NE + e] = __float2half(a1);   // coalesced 2B/lane
        W2[s * NE + e] = __float2half(a2);
        #pragma unroll
        for (int g = 0; g < NB; ++g) {
            float cn = fmaf(kk[g], cc[g], -cp[g]);
            cp[g] = cc[g];
            cc[g] = cn;
        }
    }
}

// Nk dot: planar f16 W row (LDS, 8 lanes share -> broadcast) x f32 x-row.
// Two 6-chunk halves bound in-flight LDS-load registers (r6-proven).
__device__ __forceinline__ float nkdot(const __half* __restrict__ wrow,
                                       const float* __restrict__ xr) {
    float acc = 0.0f;
    #pragma unroll
    for (int h = 0; h < 2; ++h) {
        #pragma unroll
        for (int j = h * 6; j < h * 6 + 6; ++j) {
            float4 raw = *(const float4*)(wrow + 8 * j);
            const __half2* hp = (const __half2*)&raw;
            float2 c0 = __half22float2(hp[0]);
            float2 c1 = __half22float2(hp[1]);
            float2 c2 = __half22float2(hp[2]);
            float2 c3 = __half22float2(hp[3]);
            float4 x0 = *(const float4*)(xr + 8 * j);
            float4 x1 = *(const float4*)(xr + 8 * j + 4);
            acc = fmaf(c0.x, x0.x, acc); acc = fmaf(c0.y, x0.y, acc);
            acc = fmaf(c1.x, x0.z, acc); acc = fmaf(c1.y, x0.w, acc);
            acc = fmaf(c2.x, x1.x, acc); acc = fmaf(c2.y, x1.y, acc);
            acc = fmaf(c3.x, x1.z, acc); acc = fmaf(c3.y, x1.w, acc);
        }
    }
    return acc;
}

__device__ __forceinline__ void stage_W(__half* __restrict__ wh,
                                        const __half* __restrict__ Wg,
                                        int tid) {
    for (int cidx = tid; cidx < NE / 8; cidx += NT_C) {   // 1152 float4 chunks
        const int i = cidx / 12;
        const int j = (cidx % 12) * 8;
        *(float4*)(wh + i * HPAD + j) = *(const float4*)(Wg + cidx * 8);
    }
}

// ---------------- Consumer: round-0 proven structure; W1 stage moved after B1 ------
// 512 thr = 8 waves; 1024 blocks = exactly 4/CU, zero tail.
// (i,b) mapping everywhere: 8 lanes share one M/W row -> ~8 cache lines per wave
// load (row-per-lane mapping measured catastrophic in r1: 64 lines/instr,
// consumer 44->110us, occupancy 22%).
// NO min-waves clause ((512,N) produced destructive VGPR caps in r5/r9).
__global__ void __launch_bounds__(NT_C)
consumer(const float* __restrict__ seq,
         const float* __restrict__ M1, const float* __restrict__ Wres1,
         const float* __restrict__ M2,
         const float* __restrict__ g1, const float* __restrict__ b1,
         const float* __restrict__ g2, const float* __restrict__ b2,
         const __half* __restrict__ W1g, const __half* __restrict__ W2g,
         float* __restrict__ out) {
    __shared__ __align__(16) __half wh [D_OUT * HPAD];   // 19968 B (one layer at a time)
    __shared__ __align__(16) float  xn [B_SZ * SPAD];    //  3200 B
    __shared__ __align__(16) float  x1b[B_SZ * SPAD];    //  3200 B; xin alias pre-Nk1
    // total 26368 B

    const int s   = blockIdx.x;
    const int tid = threadIdx.x;

    // stage seq rows only (into x1b alias space); W1 stage issued after B1 so
    // its HBM latency drains at B2, hidden under GEMV1 (which never touches wh).
    {
        int b = tid >> 6, k = tid & 63;
        x1b[b * SPAD + k] = seq[((size_t)b * S_LEN + s) * D_IN + k];   // xin alias
    }
    __syncthreads();   // B1 (seq staged)

    stage_W(wh, W1g + (size_t)s * NE, tid);   // drains at B2, overlapped with GEMV1

    // ---- GEMV1: xt = seq@M1^T -> xn;  rs = seq@Wres1^T -> registers ----
    float ar0 = 0.0f, ar1 = 0.0f;
    for (int pass = 0; pass < 2; ++pass) {
        int idx = tid + pass * NT_C;
        if (idx >= B_SZ * D_OUT) break;
        int i = idx >> 3, b = idx & 7;
        const float4* m  = (const float4*)(M1 + i * D_IN);
        const float4* wr = (const float4*)(Wres1 + i * D_IN);
        const float*  xr = x1b + b * SPAD;   // xin alias
        float at = 0.0f, ar = 0.0f;
        #pragma unroll
        for (int k = 0; k < D_IN / 4; ++k) {
            float4 mv = m[k], rv = wr[k];
            float x0 = xr[4*k], x1 = xr[4*k+1], x2 = xr[4*k+2], x3 = xr[4*k+3];
            at = fmaf(mv.x, x0, fmaf(mv.y, x1, fmaf(mv.z, x2, fmaf(mv.w, x3, at))));
            ar = fmaf(rv.x, x0, fmaf(rv.y, x1, fmaf(rv.z, x2, fmaf(rv.w, x3, ar))));
        }
        xn[b * SPAD + i] = at;
        if (pass == 0) ar0 = ar; else ar1 = ar;
    }
    __syncthreads();   // B2  (xin alias dead from here; W1 staged)

    // ---- LN1: wave64 per batch row ----
    {
        const int b = tid >> 6, lane = tid & 63;
        const bool lo = (lane < 32);
        float* row = xn + b * SPAD;
        float v0 = row[lane];
        float v1 = lo ? row[64 + lane] : 0.0f;
        float sum = v0 + v1, sq = fmaf(v0, v0, v1 * v1);
        #pragma unroll
        for (int off = 32; off > 0; off >>= 1) {
            sum += __shfl_down(sum, off, 64);
            sq  += __shfl_down(sq,  off, 64);
        }
        sum = __shfl(sum, 0, 64);
        sq  = __shfl(sq,  0, 64);
        const float mu  = sum * (1.0f / 96.0f);
        const float var = fmaf(sq, 1.0f / 96.0f, -(mu * mu));
        const float rs  = rsqrtf(var + 1e-5f);
        row[lane] = fmaf((v0 - mu) * rs, g1[lane], b1[lane]);
        if (lo) row[64 + lane] = fmaf((v1 - mu) * rs, g1[64 + lane], b1[64 + lane]);
    }
    __syncthreads();   // B3

    // ---- Nk1 + residual(regs) -> x1b ----
    for (int pass = 0; pass < 2; ++pass) {
        int idx = tid + pass * NT_C;
        if (idx >= B_SZ * D_OUT) break;
        int i = idx >> 3, b = idx & 7;
        float ar = (pass == 0) ? ar0 : ar1;
        x1b[b * SPAD + i] = ar + nkdot(wh + i * HPAD, xn + b * SPAD);
    }
    __syncthreads();   // B4: W1 reads + x1b writes complete

    // restage wh <- W2[s]; GEMV2 overlaps (doesn't touch wh), B5 covers both.
    stage_W(wh, W2g + (size_t)s * NE, tid);

    // ---- GEMV2: xt2 = x1 @ M2^T -> xn ----
    for (int pass = 0; pass < 2; ++pass) {
        int idx = tid + pass * NT_C;
        if (idx >= B_SZ * D_OUT) break;
        int i = idx >> 3, b = idx & 7;
        const float4* m  = (const float4*)(M2 + i * D_OUT);
        const float*  xr = x1b + b * SPAD;
        float at = 0.0f;
        #pragma unroll
        for (int k = 0; k < D_OUT / 4; ++k) {
            float4 mv = m[k];
            at = fmaf(mv.x, xr[4*k], fmaf(mv.y, xr[4*k+1],
                 fmaf(mv.z, xr[4*k+2], fmaf(mv.w, xr[4*k+3], at))));
        }
        xn[b * SPAD + i] = at;
    }
    __syncthreads();   // B5

    // ---- LN2 ----
    {
        const int b = tid >> 6, lane = tid & 63;
        const bool lo = (lane < 32);
        float* row = xn + b * SPAD;
        float v0 = row[lane];
        float v1 = lo ? row[64 + lane] : 0.0f;
        float sum = v0 + v1, sq = fmaf(v0, v0, v1 * v1);
        #pragma unroll
        for (int off = 32; off > 0; off >>= 1) {
            sum += __shfl_down(sum, off, 64);
            sq  += __shfl_down(sq,  off, 64);
        }
        sum = __shfl(sum, 0, 64);
        sq  = __shfl(sq,  0, 64);
        const float mu  = sum * (1.0f / 96.0f);
        const float var = fmaf(sq, 1.0f / 96.0f, -(mu * mu));
        const float rs  = rsqrtf(var + 1e-5f);
        row[lane] = fmaf((v0 - mu) * rs, g2[lane], b2[lane]);
        if (lo) row[64 + lane] = fmaf((v1 - mu) * rs, g2[64 + lane], b2[64 + lane]);
    }
    __syncthreads();   // B6

    // ---- Nk2 + identity residual -> out ----
    for (int pass = 0; pass < 2; ++pass) {
        int idx = tid + pass * NT_C;
        if (idx >= B_SZ * D_OUT) break;
        int i = idx >> 3, b = idx & 7;
        float acc = nkdot(wh + i * HPAD, xn + b * SPAD);
        out[((size_t)b * S_LEN + s) * D_OUT + i] = acc + x1b[b * SPAD + i];
    }
}

// ---------------- Fallback (round-1 proven kernel) if ws too small ----------------
__global__ void __launch_bounds__(NT_W)
hier_fallback(const float* __restrict__ seq,  const float* __restrict__ M1,
              const float* __restrict__ P1,   const float* __restrict__ Wres1,
              const float* __restrict__ g1,   const float* __restrict__ b1,
              const float* __restrict__ M2,   const float* __restrict__ P2,
              const float* __restrict__ g2,   const float* __restrict__ b2,
              float* __restrict__ out) {
    __shared__ __align__(16) float w[D_OUT * SPAD];
    __shared__ __align__(16) float xin[B_SZ * XPAD];
    __shared__ __align__(16) float xn [B_SZ * SPAD];
    __shared__ __align__(16) float x1b[B_SZ * SPAD];
    const int s = blockIdx.x, tid = threadIdx.x;
    const float sf = (float)s;

    for (int idx = tid; idx < B_SZ * D_IN; idx += NT_W) {
        int b = idx >> 6, k = idx & (D_IN - 1);
        xin[b * XPAD + k] = seq[(b * S_LEN + s) * D_IN + k];
    }
    for (int e = tid; e < NE; e += NT_W) {
        float pl[8];
        *(float4*)&pl[0] = *(const float4*)(P1 + e * NB);
        *(float4*)&pl[4] = *(const float4*)(P1 + e * NB + 4);
        float acc = 0.0f;
        #pragma unroll
        for (int g = 0; g < NB; ++g) {
            float v = sf * __builtin_amdgcn_rcpf((float)(e * NB + 2 + g));
            acc = fmaf(pl[g], cos_rev(v), acc);
        }
        int i = e / D_OUT;
        w[e + (SPAD - D_OUT) * i] = acc;
    }
    __syncthreads();
    for (int idx = tid; idx < B_SZ * D_OUT; idx += NT_W) {
        int i = idx >> 3, b = idx & 7;
        const float4* m  = (const float4*)(M1 + i * D_IN);
        const float4* wr = (const float4*)(Wres1 + i * D_IN);
        const float*  xr = xin + b * XPAD;
        float at = 0.0f, ar = 0.0f;
        #pragma unroll
        for (int k = 0; k < D_IN / 4; ++k) {
            float4 mv = m[k], rv = wr[k];
            float x0 = xr[4*k], x1 = xr[4*k+1], x2 = xr[4*k+2], x3 = xr[4*k+3];
            at = fmaf(mv.x, x0, fmaf(mv.y, x1, fmaf(mv.z, x2, fmaf(mv.w, x3, at))));
            ar = fmaf(rv.x, x0, fmaf(rv.y, x1, fmaf(rv.z, x2, fmaf(rv.w, x3, ar))));
        }
        xn [b * SPAD + i] = at;
        x1b[b * SPAD + i] = ar;
    }
    __syncthreads();
    {
        const int b = tid >> 5, rr = tid & 31;
        float* row = xn + b * SPAD;
        float v0 = row[rr], v1 = row[rr + 32], v2 = row[rr + 64];
        float sum = v0 + v1 + v2, sq = fmaf(v0, v0, fmaf(v1, v1, v2 * v2));
        #pragma unroll
        for (int off = 16; off > 0; off >>= 1) {
            sum += __shfl_down(sum, off, 32);
            sq  += __shfl_down(sq,  off, 32);
        }
        sum = __shfl(sum, 0, 32); sq = __shfl(sq, 0, 32);
        float mu = sum * (1.0f/96.0f), var = fmaf(sq, 1.0f/96.0f, -(mu*mu));
        float rs = rsqrtf(var + 1e-5f);
        row[rr]      = fmaf((v0 - mu) * rs, g1[rr],      b1[rr]);
        row[rr + 32] = fmaf((v1 - mu) * rs, g1[rr + 32], b1[rr + 32]);
        row[rr + 64] = fmaf((v2 - mu) * rs, g1[rr + 64], b1[rr + 64]);
    }
    __syncthreads();
    for (int idx = tid; idx < B_SZ * D_OUT; idx += NT_W) {
        int i = idx >> 3, b = idx & 7;
        const float* wrow = w + i * SPAD;
        const float* xr   = xn + b * SPAD;
        float acc = 0.0f;
        #pragma unroll
        for (int j = 0; j < D_OUT / 4; ++j) {
            float4 wv = *(const float4*)(wrow + 4 * j);
            float4 xv = *(const float4*)(xr + 4 * j);
            acc = fmaf(wv.x, xv.x, fmaf(wv.y, xv.y, fmaf(wv.z, xv.z, fmaf(wv.w, xv.w, acc))));
        }
        x1b[b * SPAD + i] += acc;
    }
    __syncthreads();
    for (int e = tid; e < NE; e += NT_W) {
        float pl[8];
        *(float4*)&pl[0] = *(const float4*)(P2 + e * NB);
        *(float4*)&pl[4] = *(const float4*)(P2 + e * NB + 4);
        float acc = 0.0f;
        #pragma unroll
        for (int g = 0; g < NB; ++g) {
            float v = sf * __builtin_amdgcn_rcpf((float)(e * NB + 2 + g));
            acc = fmaf(pl[g], cos_rev(v), acc);
        }
        int i = e / D_OUT;
        w[e + (SPAD - D_OUT) * i] = acc;
    }
    for (int idx = tid; idx < B_SZ * D_OUT; idx += NT_W) {
        int i = idx >> 3, b = idx & 7;
        const float4* m  = (const float4*)(M2 + i * D_OUT);
        const float*  xr = x1b + b * SPAD;
        float at = 0.0f;
        #pragma unroll
        for (int k = 0; k < D_OUT / 4; ++k) {
            float4 mv = m[k];
            at = fmaf(mv.x, xr[4*k], fmaf(mv.y, xr[4*k+1],
                 fmaf(mv.z, xr[4*k+2], fmaf(mv.w, xr[4*k+3], at))));
        }
        xn[b * SPAD + i] = at;
    }
    __syncthreads();
    {
        const int b = tid >> 5, rr = tid & 31;
        float* row = xn + b * SPAD;
        float v0 = row[rr], v1 = row[rr + 32], v2 = row[rr + 64];
        float sum = v0 + v1 + v2, sq = fmaf(v0, v0, fmaf(v1, v1, v2 * v2));
        #pragma unroll
        for (int off = 16; off > 0; off >>= 1) {
            sum += __shfl_down(sum, off, 32);
            sq  += __shfl_down(sq,  off, 32);
        }
        sum = __shfl(sum, 0, 32); sq = __shfl(sq, 0, 32);
        float mu = sum * (1.0f/96.0f), var = fmaf(sq, 1.0f/96.0f, -(mu*mu));
        float rs = rsqrtf(var + 1e-5f);
        row[rr]      = fmaf((v0 - mu) * rs, g2[rr],      b2[rr]);
        row[rr + 32] = fmaf((v1 - mu) * rs, g2[rr + 32], b2[rr + 32]);
        row[rr + 64] = fmaf((v2 - mu) * rs, g2[rr + 64], b2[rr + 64]);
    }
    __syncthreads();
    for (int idx = tid; idx < B_SZ * D_OUT; idx += NT_W) {
        int i = idx >> 3, b = idx & 7;
        const float* wrow = w + i * SPAD;
        const float* xr   = xn + b * SPAD;
        float acc = 0.0f;
        #pragma unroll
        for (int j = 0; j < D_OUT / 4; ++j) {
            float4 wv = *(const float4*)(wrow + 4 * j);
            float4 xv = *(const float4*)(xr + 4 * j);
            acc = fmaf(wv.x, xv.x, fmaf(wv.y, xv.y, fmaf(wv.z, xv.z, fmaf(wv.w, xv.w, acc))));
        }
        out[(b * S_LEN + s) * D_OUT + i] = acc + x1b[b * SPAD + i];
    }
}

extern "C" void kernel_launch(void* const* d_in, const int* in_sizes, int n_in,
                              void* d_out, int out_size, void* d_ws, size_t ws_size,
                              hipStream_t stream) {
    const float* seq   = (const float*)d_in[0];
    const float* M1    = (const float*)d_in[1];
    const float* P1    = (const float*)d_in[2];
    const float* Wres1 = (const float*)d_in[3];
    const float* g1    = (const float*)d_in[4];
    const float* b1    = (const float*)d_in[5];
    const float* M2    = (const float*)d_in[6];
    const float* P2    = (const float*)d_in[7];
    const float* g2    = (const float*)d_in[8];
    const float* b2    = (const float*)d_in[9];
    float* out = (float*)d_out;

    const size_t need = (size_t)2 * S_LEN * NE * sizeof(__half);   // 37.75 MB
    if (ws_size >= need) {
        __half* W1 = (__half*)d_ws;
        __half* W2 = W1 + (size_t)S_LEN * NE;
        w_kernel<<<dim3(NWBLK), dim3(NT_W), 0, stream>>>(P1, P2, W1, W2);
        consumer<<<dim3(S_LEN), dim3(NT_C), 0, stream>>>(
            seq, M1, Wres1, M2, g1, b1, g2, b2, W1, W2, out);
    } else {
        hier_fallback<<<dim3(S_LEN), dim3(NT_W), 0, stream>>>(
            seq, M1, P1, Wres1, g1, b1, M2, P2, g2, b2, out);
    }
}